// Round 1
// 527.435 us; speedup vs baseline: 1.3225x; 1.3225x over previous
//
#include <hip/hip_runtime.h>

// RadarRnn1: 4-layer tanh RNN (B=512,S=1024,IN=64,H=32) + per-step FC + softmax over S.
// R9: rnn_kernel was latency-bound: 512 waves on 1024 SIMDs (Occupancy 5.85%,
// VALUBusy 24%), per-tick chain ~1145cy vs ~230cy of issued VALU. Restructure:
// one block of 4 waves per batch element, wave = layer (same skewed pipeline the
// single wave ran in-wave: wave l computes timestep t at iteration n = t+l).
//   - 2048 waves -> 8 waves/CU (2/SIMD): independent blocks overlap stalls.
//   - per-iteration critical path is ONE layer (16 fdot2 + tanh), not four.
//   - inter-layer handoff via the same f16-packed LDS double-buffer; one
//     barrier per iteration. NOT __syncthreads(): that drains vmcnt(0) and
//     would expose the u0 global-load latency every tick. Cross-wave data is
//     LDS-only, so an lgkmcnt(0)-only s_barrier is sufficient; u0 prefetch
//     (widened to distance 8) stays in flight across barriers.
// u0_kernel / softmax_kernel unchanged from R8.

#define BB 512
#define SS 1024
#define INF 64
#define HH 32
#define LL 4

typedef __fp16 v2h __attribute__((ext_vector_type(2)));

__device__ __forceinline__ v2h bch(unsigned u) { return __builtin_bit_cast(v2h, u); }
__device__ __forceinline__ unsigned bcu(v2h h) { return __builtin_bit_cast(unsigned, h); }

// v = v + dpp_mov(v, CTRL); bound_ctrl=1 -> out-of-range lanes contribute 0.
template <int CTRL>
__device__ __forceinline__ float dpp_add(float v) {
  int y = __builtin_amdgcn_update_dpp(0, __float_as_int(v), CTRL, 0xF, 0xF, true);
  return v + __int_as_float(y);
}
template <int CTRL>
__device__ __forceinline__ float dpp_mov(float v) {
  int y = __builtin_amdgcn_update_dpp(0, __float_as_int(v), CTRL, 0xF, 0xF, true);
  return __int_as_float(y);
}

// tanh(a) = 1 - 2/(e^{2a}+1); e^{2a} = 2^(a * 2/ln2). v_exp + v_rcp + fma.
__device__ __forceinline__ float tanh_fast(float a) {
  const float e = __builtin_amdgcn_exp2f(a * 2.885390081777927f);
  const float r = __builtin_amdgcn_rcpf(e + 1.0f);
  return __builtin_fmaf(-2.0f, r, 1.0f);
}

// 16-half dot: w[8] packed f16 pairs against value-passed LDS data.
__device__ __forceinline__ float dot16v(const v2h* w, uint4 u0, uint4 u1) {
  float a = 0.f, c = 0.f;
  a = __builtin_amdgcn_fdot2(w[0], bch(u0.x), a, false);
  c = __builtin_amdgcn_fdot2(w[1], bch(u0.y), c, false);
  a = __builtin_amdgcn_fdot2(w[2], bch(u0.z), a, false);
  c = __builtin_amdgcn_fdot2(w[3], bch(u0.w), c, false);
  a = __builtin_amdgcn_fdot2(w[4], bch(u1.x), a, false);
  c = __builtin_amdgcn_fdot2(w[5], bch(u1.y), c, false);
  a = __builtin_amdgcn_fdot2(w[6], bch(u1.z), a, false);
  c = __builtin_amdgcn_fdot2(w[7], bch(u1.w), c, false);
  return a + c;
}

// lgkmcnt-only barrier: drains LDS ops (cross-wave handoff) but leaves global
// loads/stores in flight (u0 prefetch, hfin/logit stores). "memory" clobber
// pins all memory ops on their side of the barrier at IR level.
#define BAR() asm volatile("s_waitcnt lgkmcnt(0)\n\ts_barrier" ::: "memory")

// ---------------- u0 = x @ W_ih0^T + (b_ih0 + b_hh0) ----------------
__global__ __launch_bounds__(256) void u0_kernel(
    const float* __restrict__ x, const float* __restrict__ W_ih0,
    const float* __restrict__ b_ih, const float* __restrict__ b_hh,
    float* __restrict__ u0) {
  __shared__ float Wl[HH * INF];  // [u][k]
  __shared__ float bl[HH];
  const int tid = threadIdx.x;
  {
    const float4* src = (const float4*)W_ih0;
    float4* dst = (float4*)Wl;
    dst[tid] = src[tid];
    dst[tid + 256] = src[tid + 256];
    if (tid < HH) bl[tid] = b_ih[tid] + b_hh[tid];
  }
  __syncthreads();

  const int row = blockIdx.x * 256 + tid;  // 2048 blocks x 256 rows
  const float4* xr = (const float4*)(x + (size_t)row * INF);
  float acc[HH];
#pragma unroll
  for (int u = 0; u < HH; ++u) acc[u] = bl[u];
#pragma unroll 4
  for (int kc = 0; kc < 16; ++kc) {
    const float4 xv = xr[kc];
#pragma unroll
    for (int u = 0; u < HH; ++u) {
      const float4 wv = ((const float4*)Wl)[u * 16 + kc];  // wave-broadcast
      acc[u] += wv.x * xv.x + wv.y * xv.y + wv.z * xv.z + wv.w * xv.w;
    }
  }
  float4* op = (float4*)(u0 + (size_t)row * HH);
#pragma unroll
  for (int j = 0; j < 8; ++j)
    op[j] = make_float4(acc[4 * j], acc[4 * j + 1], acc[4 * j + 2], acc[4 * j + 3]);
}

// ---------------- recurrent kernel: 4 waves (one per layer) per batch ----------------
__global__ __launch_bounds__(256, 2) void rnn_kernel(
    const float* __restrict__ u0g_all, const float* __restrict__ h_state,
    const float* __restrict__ W_ih_rest, const float* __restrict__ W_hh,
    const float* __restrict__ b_ih, const float* __restrict__ b_hh,
    const float* __restrict__ fc_w, const float* __restrict__ fc_b,
    float* __restrict__ out) {
  __shared__ int hb[LL][2][16];  // [layer][parity][unit-pair] f16x2
  __shared__ float lbuf[64];     // logit staging (wave 3, flushed every 64 ticks)

  const int tid  = threadIdx.x;
  const int wid  = tid >> 6;   // wave id == layer id
  const int lane = tid & 63;
  const int b    = blockIdx.x; // one batch element per block
  const int ks   = lane & 1;   // k-split half
  const int h    = lane >> 1;  // output unit 0..31

  // weights: f16-packed h-matrices only (x-part of layer 0 lives in u0)
  v2h wih[8], whh[8];
  {
    const float2* ph = (const float2*)(W_hh + (size_t)(wid * HH + h) * HH + ks * 16);
#pragma unroll
    for (int j = 0; j < 8; ++j) whh[j] = __builtin_amdgcn_cvt_pkrtz(ph[j].x, ph[j].y);
  }
  float bias = 0.f;  // layer 0 bias folded into u0
  if (wid > 0) {
    const float2* pi =
        (const float2*)(W_ih_rest + (size_t)((wid - 1) * HH + h) * HH + ks * 16);
#pragma unroll
    for (int j = 0; j < 8; ++j) wih[j] = __builtin_amdgcn_cvt_pkrtz(pi[j].x, pi[j].y);
    bias = b_ih[wid * HH + h] + b_hh[wid * HH + h];
  }
  const float fcwh = fc_w[h] * 0.5f;  // both ks lanes hold hv -> 64-lane sum is 2x
  const float fcb  = fc_b[0];

  // initial hidden state -> parity 1 (first read parity), f16-packed
  if (lane < 16) {
    float a = h_state[(size_t)(wid * BB + b) * HH + 2 * lane];
    float c = h_state[(size_t)(wid * BB + b) * HH + 2 * lane + 1];
    hb[wid][1][lane] = (int)bcu(__builtin_amdgcn_cvt_pkrtz(a, c));
  }

  const float* ug = u0g_all + (size_t)b * SS * HH;
  float ur[8];  // rotating u0 prefetch regs (wave 0 only), distance 8
  if (wid == 0) {
#pragma unroll
    for (int i = 0; i < 8; ++i) ur[i] = ug[i * HH + h];
  }
  float* const outrow = out + (size_t)b * SS;
  float* const hfin   = out + (size_t)BB * SS;

  __syncthreads();  // init visible to all waves (one-time full barrier is fine)

  auto ld2 = [&](const int* p, uint4& A, uint4& B) __attribute__((always_inline)) {
    const uint4* q = (const uint4*)p;
    A = q[0]; B = q[1];
  };
  // pack own hv with neighbor-unit hv (quad_perm [2,3,2,3]) and store by 16 lanes
  auto store_h = [&](int l, int par, float hv) __attribute__((always_inline)) {
    float partner = dpp_mov<0xEE>(hv);
    if ((lane & 3) == 0)
      hb[l][par][lane >> 2] = (int)bcu(__builtin_amdgcn_cvt_pkrtz(hv, partner));
  };

  // Schedule: wave l computes timestep t at iteration n = t + l.
  // All layers store h(t) to parity t&1; own h(t-1) read from parity (t&1)^1;
  // input h(t) of layer l-1 read from parity t&1 (written one barrier earlier).
  // NITER = 1032: multiple of 8 (prefetch rotation), >= SS-1+3.
  if (wid == 0) {
    for (int n = 0; n < 1032; n += 8) {
#pragma unroll
      for (int j = 0; j < 8; ++j) {
        BAR();
        const int t = n + j;
        if (t < SS) {  // wave-uniform
          const int par = t & 1;
          uint4 Ha, Hb;
          ld2(&hb[0][par ^ 1][ks * 8], Ha, Hb);
          float acc = dot16v(whh, Ha, Hb);
          acc = dpp_add<0xB1>(acc) + ur[j];  // u0 holds x-part + full bias0
          const float hv = tanh_fast(acc);
          store_h(0, par, hv);
          if (t == SS - 1 && ks == 0) hfin[(0 * BB + b) * HH + h] = hv;
          int tl = t + 8; tl = (tl < SS) ? tl : (SS - 1);
          ur[j] = ug[tl * HH + h];  // reload for t+8; survives BAR (no vmcnt drain)
        }
      }
    }
  } else if (wid < 3) {
    for (int n = 0; n < 1032; n += 8) {
#pragma unroll
      for (int j = 0; j < 8; ++j) {
        BAR();
        const int t = n + j - wid;
        if (t >= 0 && t < SS) {  // wave-uniform
          const int par = t & 1;
          uint4 Ia, Ib, Ha, Hb;
          ld2(&hb[wid - 1][par][ks * 8], Ia, Ib);  // input: layer below, time t
          ld2(&hb[wid][par ^ 1][ks * 8], Ha, Hb);  // own h, time t-1
          float acc = dot16v(wih, Ia, Ib) + dot16v(whh, Ha, Hb);
          acc = dpp_add<0xB1>(acc) + bias;
          const float hv = tanh_fast(acc);
          store_h(wid, par, hv);
          if (t == SS - 1 && ks == 0) hfin[(wid * BB + b) * HH + h] = hv;
        }
      }
    }
  } else {  // wave 3: layer 3 + per-step FC + logit staging
    for (int n = 0; n < 1032; n += 8) {
#pragma unroll
      for (int j = 0; j < 8; ++j) {
        BAR();
        const int t = n + j - 3;
        if (t >= 0 && t < SS) {  // wave-uniform
          const int par = t & 1;
          uint4 Ia, Ib, Ha, Hb;
          ld2(&hb[2][par][ks * 8], Ia, Ib);
          ld2(&hb[3][par ^ 1][ks * 8], Ha, Hb);
          float acc = dot16v(wih, Ia, Ib) + dot16v(whh, Ha, Hb);
          acc = dpp_add<0xB1>(acc) + bias;
          const float hv = tanh_fast(acc);
          store_h(3, par, hv);
          if (t == SS - 1 && ks == 0) hfin[(3 * BB + b) * HH + h] = hv;
          // FC reduce via DPP cascade; lane 63 holds the 64-lane sum.
          float v = hv * fcwh;
          v = dpp_add<0x111>(v);  // row_shr:1
          v = dpp_add<0x112>(v);  // row_shr:2
          v = dpp_add<0x114>(v);  // row_shr:4
          v = dpp_add<0x118>(v);  // row_shr:8
          v = dpp_add<0x142>(v);  // row_bcast:15
          v = dpp_add<0x143>(v);  // row_bcast:31
          if (lane == 63) lbuf[t & 63] = v + fcb;
          if ((t & 63) == 63) {  // coalesced flush of 64 logits
            float lv = lbuf[lane];
            outrow[t - 63 + lane] = lv;
          }
        }
      }
    }
  }
}

__global__ __launch_bounds__(256) void softmax_kernel(float* __restrict__ out) {
  __shared__ float red[8];
  const int row = blockIdx.x;
  float* p = out + (size_t)row * SS;
  const int tid = threadIdx.x;
  float4 v = ((const float4*)p)[tid];  // 256 threads x 4 = 1024 logits
  float m = fmaxf(fmaxf(v.x, v.y), fmaxf(v.z, v.w));
#pragma unroll
  for (int d = 32; d >= 1; d >>= 1) m = fmaxf(m, __shfl_xor(m, d));
  if ((tid & 63) == 0) red[tid >> 6] = m;
  __syncthreads();
  m = fmaxf(fmaxf(red[0], red[1]), fmaxf(red[2], red[3]));
  const float e0 = __expf(v.x - m), e1 = __expf(v.y - m);
  const float e2 = __expf(v.z - m), e3 = __expf(v.w - m);
  float s = (e0 + e1) + (e2 + e3);
#pragma unroll
  for (int d = 32; d >= 1; d >>= 1) s += __shfl_xor(s, d);
  if ((tid & 63) == 0) red[4 + (tid >> 6)] = s;
  __syncthreads();
  s = (red[4] + red[5]) + (red[6] + red[7]);
  const float inv = 1.0f / s;
  float4 o;
  o.x = e0 * inv; o.y = e1 * inv; o.z = e2 * inv; o.w = e3 * inv;
  ((float4*)p)[tid] = o;
}

extern "C" void kernel_launch(void* const* d_in, const int* in_sizes, int n_in,
                              void* d_out, int out_size, void* d_ws, size_t ws_size,
                              hipStream_t stream) {
  const float* x         = (const float*)d_in[0];
  const float* h_state   = (const float*)d_in[1];
  const float* W_ih0     = (const float*)d_in[2];
  const float* W_ih_rest = (const float*)d_in[3];
  const float* W_hh      = (const float*)d_in[4];
  const float* b_ih      = (const float*)d_in[5];
  const float* b_hh      = (const float*)d_in[6];
  const float* fc_w      = (const float*)d_in[7];
  const float* fc_b      = (const float*)d_in[8];
  float* out = (float*)d_out;
  float* u0  = (float*)d_ws;  // [B,S,32] fp32 = 67 MB scratch

  hipLaunchKernelGGL(u0_kernel, dim3((BB * SS) / 256), dim3(256), 0, stream,
                     x, W_ih0, b_ih, b_hh, u0);
  hipLaunchKernelGGL(rnn_kernel, dim3(BB), dim3(256), 0, stream,
                     u0, h_state, W_ih_rest, W_hh, b_ih, b_hh, fc_w, fc_b, out);
  hipLaunchKernelGGL(softmax_kernel, dim3(BB), dim3(256), 0, stream, out);
}

// Round 2
// 457.016 us; speedup vs baseline: 1.5262x; 1.1541x over previous
//
#include <hip/hip_runtime.h>

// RadarRnn1: 4-layer tanh RNN (B=512,S=1024,IN=64,H=32) + per-step FC + softmax over S.
// R10: R9 measured 725cy per barrier-iteration with only ~145cy of VALU issue per
// wave (VALUBusy 40%, 2 waves/SIMD): ~60% of each iteration is barrier/LDS dead
// time. Grid is capped at 512 blocks (one per batch), so amortize instead:
//   - TWO timesteps per barrier (skew-2 pipeline): wave l computes t=2(n-l),
//     2(n-l)+1 at iteration n. Both inputs from layer l-1 were produced last
//     iteration; the intra-pair h(t)->h(t+1) dependency is an in-wave LDS
//     round trip (DS is in-order within a wave, no barrier). 1032 -> 516
//     barriers; per-tick critical path ~225cy vs 725.
//   - Wave 3 was the pacer (2 dots + 6-dpp FC cascade). Move the FC reduce to
//     wave 0 (lightest wave): wave 3 publishes f32 hv to LDS, wave 0 reduces it
//     one iteration later with the identical f32 cascade -> bit-identical
//     logits, balanced waves.
//   - Double-buffer by iteration parity (n&1): writer fills buf n&1, reader
//     consumes buf (n-1)&1; reads are drained by each wave's own lgkmcnt(0)
//     before the next barrier, so the buffer is free to overwrite at n+2.
// u0_kernel / softmax_kernel unchanged.

#define BB 512
#define SS 1024
#define INF 64
#define HH 32
#define LL 4

typedef __fp16 v2h __attribute__((ext_vector_type(2)));

__device__ __forceinline__ v2h bch(unsigned u) { return __builtin_bit_cast(v2h, u); }
__device__ __forceinline__ unsigned bcu(v2h h) { return __builtin_bit_cast(unsigned, h); }

// v = v + dpp_mov(v, CTRL); bound_ctrl=1 -> out-of-range lanes contribute 0.
template <int CTRL>
__device__ __forceinline__ float dpp_add(float v) {
  int y = __builtin_amdgcn_update_dpp(0, __float_as_int(v), CTRL, 0xF, 0xF, true);
  return v + __int_as_float(y);
}
template <int CTRL>
__device__ __forceinline__ float dpp_mov(float v) {
  int y = __builtin_amdgcn_update_dpp(0, __float_as_int(v), CTRL, 0xF, 0xF, true);
  return __int_as_float(y);
}

// tanh(a) = 1 - 2/(e^{2a}+1); e^{2a} = 2^(a * 2/ln2). v_exp + v_rcp + fma.
__device__ __forceinline__ float tanh_fast(float a) {
  const float e = __builtin_amdgcn_exp2f(a * 2.885390081777927f);
  const float r = __builtin_amdgcn_rcpf(e + 1.0f);
  return __builtin_fmaf(-2.0f, r, 1.0f);
}

// 16-half dot: w[8] packed f16 pairs against value-passed LDS data.
__device__ __forceinline__ float dot16v(const v2h* w, uint4 u0, uint4 u1) {
  float a = 0.f, c = 0.f;
  a = __builtin_amdgcn_fdot2(w[0], bch(u0.x), a, false);
  c = __builtin_amdgcn_fdot2(w[1], bch(u0.y), c, false);
  a = __builtin_amdgcn_fdot2(w[2], bch(u0.z), a, false);
  c = __builtin_amdgcn_fdot2(w[3], bch(u0.w), c, false);
  a = __builtin_amdgcn_fdot2(w[4], bch(u1.x), a, false);
  c = __builtin_amdgcn_fdot2(w[5], bch(u1.y), c, false);
  a = __builtin_amdgcn_fdot2(w[6], bch(u1.z), a, false);
  c = __builtin_amdgcn_fdot2(w[7], bch(u1.w), c, false);
  return a + c;
}

// lgkmcnt-only barrier: drains LDS ops (cross-wave handoff) but leaves global
// loads/stores in flight (u0 prefetch, hfin/logit stores).
#define BAR() asm volatile("s_waitcnt lgkmcnt(0)\n\ts_barrier" ::: "memory")

// ---------------- u0 = x @ W_ih0^T + (b_ih0 + b_hh0) ----------------
__global__ __launch_bounds__(256) void u0_kernel(
    const float* __restrict__ x, const float* __restrict__ W_ih0,
    const float* __restrict__ b_ih, const float* __restrict__ b_hh,
    float* __restrict__ u0) {
  __shared__ float Wl[HH * INF];  // [u][k]
  __shared__ float bl[HH];
  const int tid = threadIdx.x;
  {
    const float4* src = (const float4*)W_ih0;
    float4* dst = (float4*)Wl;
    dst[tid] = src[tid];
    dst[tid + 256] = src[tid + 256];
    if (tid < HH) bl[tid] = b_ih[tid] + b_hh[tid];
  }
  __syncthreads();

  const int row = blockIdx.x * 256 + tid;  // 2048 blocks x 256 rows
  const float4* xr = (const float4*)(x + (size_t)row * INF);
  float acc[HH];
#pragma unroll
  for (int u = 0; u < HH; ++u) acc[u] = bl[u];
#pragma unroll 4
  for (int kc = 0; kc < 16; ++kc) {
    const float4 xv = xr[kc];
#pragma unroll
    for (int u = 0; u < HH; ++u) {
      const float4 wv = ((const float4*)Wl)[u * 16 + kc];  // wave-broadcast
      acc[u] += wv.x * xv.x + wv.y * xv.y + wv.z * xv.z + wv.w * xv.w;
    }
  }
  float4* op = (float4*)(u0 + (size_t)row * HH);
#pragma unroll
  for (int j = 0; j < 8; ++j)
    op[j] = make_float4(acc[4 * j], acc[4 * j + 1], acc[4 * j + 2], acc[4 * j + 3]);
}

// ---------------- recurrent kernel: 4 waves (one per layer), 2 ticks/barrier ----------------
__global__ __launch_bounds__(256, 2) void rnn_kernel(
    const float* __restrict__ u0g_all, const float* __restrict__ h_state,
    const float* __restrict__ W_ih_rest, const float* __restrict__ W_hh,
    const float* __restrict__ b_ih, const float* __restrict__ b_hh,
    const float* __restrict__ fc_w, const float* __restrict__ fc_b,
    float* __restrict__ out) {
  __shared__ int hb[LL][2][2][16];  // [layer][buf=n&1][slot=t&1][unit-pair f16x2]
  __shared__ float h3f[2][2][32];   // [buf][slot][unit]: wave3's f32 hv for the FC
  __shared__ float lbuf[64];        // logit staging (wave 0, flushed every 64 ticks)

  const int tid  = threadIdx.x;
  const int wid  = tid >> 6;   // wave id == layer id
  const int lane = tid & 63;
  const int b    = blockIdx.x; // one batch element per block
  const int ks   = lane & 1;   // k-split half
  const int h    = lane >> 1;  // output unit 0..31

  // weights: f16-packed h-matrices only (x-part of layer 0 lives in u0)
  v2h wih[8], whh[8];
  {
    const float2* ph = (const float2*)(W_hh + (size_t)(wid * HH + h) * HH + ks * 16);
#pragma unroll
    for (int j = 0; j < 8; ++j) whh[j] = __builtin_amdgcn_cvt_pkrtz(ph[j].x, ph[j].y);
  }
  float bias = 0.f;  // layer 0 bias folded into u0
  if (wid > 0) {
    const float2* pi =
        (const float2*)(W_ih_rest + (size_t)((wid - 1) * HH + h) * HH + ks * 16);
#pragma unroll
    for (int j = 0; j < 8; ++j) wih[j] = __builtin_amdgcn_cvt_pkrtz(pi[j].x, pi[j].y);
    bias = b_ih[wid * HH + h] + b_hh[wid * HH + h];
  }
  const float fcwh = fc_w[h] * 0.5f;  // lanes duplicate per unit -> 64-lane sum is 2x
  const float fcb  = fc_b[0];

  // initial hidden state h(-1): wave l's first read (iter n=l) is buf (l-1)&1
  // = (l+1)&1, slot 1.
  if (lane < 16) {
    float a = h_state[(size_t)(wid * BB + b) * HH + 2 * lane];
    float c = h_state[(size_t)(wid * BB + b) * HH + 2 * lane + 1];
    hb[wid][(wid + 1) & 1][1][lane] = (int)bcu(__builtin_amdgcn_cvt_pkrtz(a, c));
  }

  const float* ug = u0g_all + (size_t)b * SS * HH;
  float ur[8];  // rotating u0 prefetch (wave 0): 2 values/iter, distance 4 iters
  if (wid == 0) {
#pragma unroll
    for (int i = 0; i < 8; ++i) ur[i] = ug[i * HH + h];
  }
  float* const outrow = out + (size_t)b * SS;
  float* const hfin   = out + (size_t)BB * SS;

  __syncthreads();  // init visible to all waves

  auto ld2 = [&](const int* p, uint4& A, uint4& B) __attribute__((always_inline)) {
    const uint4* q = (const uint4*)p;
    A = q[0]; B = q[1];
  };
  // pack own hv with neighbor-unit hv (quad_perm [2,3,2,3]) and store by 16 lanes
  auto store_h = [&](int l, int buf, int slot, float hv) __attribute__((always_inline)) {
    float partner = dpp_mov<0xEE>(hv);
    if ((lane & 3) == 0)
      hb[l][buf][slot][lane >> 2] = (int)bcu(__builtin_amdgcn_cvt_pkrtz(hv, partner));
  };
  auto fcred = [&](float v) __attribute__((always_inline)) {
    v = dpp_add<0x111>(v);  // row_shr:1
    v = dpp_add<0x112>(v);  // row_shr:2
    v = dpp_add<0x114>(v);  // row_shr:4
    v = dpp_add<0x118>(v);  // row_shr:8
    v = dpp_add<0x142>(v);  // row_bcast:15
    v = dpp_add<0x143>(v);  // row_bcast:31
    return v;               // lane 63 holds the 64-lane sum
  };

  // Schedule: wave l computes t = 2(n-l), 2(n-l)+1 at iteration n (n = 0..515).
  // Writes go to hb[l][n&1][t&1]; reads come from buf (n-1)&1. Wave 0 also
  // FC-reduces wave 3's pair from iteration n-1 (h3f, f32 -> bit-identical).
  if (wid == 0) {
    for (int n0 = 0; n0 < 516; n0 += 4) {
#pragma unroll
      for (int j = 0; j < 4; ++j) {
        BAR();
        const int n = n0 + j;
        const int buf = n & 1;
        if (n < 512) {  // wave-uniform
          uint4 Ha, Hb;
          ld2(&hb[0][buf ^ 1][1][ks * 8], Ha, Hb);  // own h(2n-1)
          float acc0 = dot16v(whh, Ha, Hb);
          acc0 = dpp_add<0xB1>(acc0) + ur[2 * j];   // u0 holds x-part + bias0
          const float hv0 = tanh_fast(acc0);
          store_h(0, buf, 0, hv0);
          uint4 Ga, Gb;
          ld2(&hb[0][buf][0][ks * 8], Ga, Gb);      // own h(2n), in-wave roundtrip
          float acc1 = dot16v(whh, Ga, Gb);
          acc1 = dpp_add<0xB1>(acc1) + ur[2 * j + 1];
          const float hv1 = tanh_fast(acc1);
          store_h(0, buf, 1, hv1);
          if (n == 511 && ks == 0) hfin[(0 * BB + b) * HH + h] = hv1;
          int ta = 2 * n + 8; ta = ta < SS ? ta : SS - 1;
          int tb = 2 * n + 9; tb = tb < SS ? tb : SS - 1;
          ur[2 * j]     = ug[ta * HH + h];  // survives BAR (no vmcnt drain)
          ur[2 * j + 1] = ug[tb * HH + h];
        }
        if (n >= 4) {  // FC for wave3's pair from iter n-1: t = 2n-8, 2n-7
          const int tf = 2 * n - 7;
          float v0 = fcred(h3f[buf ^ 1][0][h] * fcwh);
          float v1 = fcred(h3f[buf ^ 1][1][h] * fcwh);
          if (lane == 63) {
            lbuf[(tf - 1) & 63] = v0 + fcb;
            lbuf[tf & 63]       = v1 + fcb;
          }
          if ((tf & 63) == 63) {  // coalesced flush of 64 logits
            float lv = lbuf[lane];
            outrow[tf - 63 + lane] = lv;
          }
        }
      }
    }
  } else if (wid < 3) {
    for (int n0 = 0; n0 < 516; n0 += 4) {
#pragma unroll
      for (int j = 0; j < 4; ++j) {
        BAR();
        const int n = n0 + j;
        const int buf = n & 1;
        if (n >= wid && n < 512 + wid) {  // wave-uniform
          uint4 I0a, I0b, I1a, I1b, Ha, Hb;
          ld2(&hb[wid - 1][buf ^ 1][0][ks * 8], I0a, I0b);  // in h(t0), layer below
          ld2(&hb[wid - 1][buf ^ 1][1][ks * 8], I1a, I1b);  // in h(t1)
          ld2(&hb[wid][buf ^ 1][1][ks * 8], Ha, Hb);        // own h(t0-1)
          float acc0 = dot16v(wih, I0a, I0b) + dot16v(whh, Ha, Hb);
          acc0 = dpp_add<0xB1>(acc0) + bias;
          const float hv0 = tanh_fast(acc0);
          store_h(wid, buf, 0, hv0);
          uint4 Ga, Gb;
          ld2(&hb[wid][buf][0][ks * 8], Ga, Gb);            // own h(t0), roundtrip
          float acc1 = dot16v(wih, I1a, I1b) + dot16v(whh, Ga, Gb);
          acc1 = dpp_add<0xB1>(acc1) + bias;
          const float hv1 = tanh_fast(acc1);
          store_h(wid, buf, 1, hv1);
          if (n == 511 + wid && ks == 0) hfin[(wid * BB + b) * HH + h] = hv1;
        }
      }
    }
  } else {  // wave 3: layer 3 + publish f32 hv for wave0's FC
    for (int n0 = 0; n0 < 516; n0 += 4) {
#pragma unroll
      for (int j = 0; j < 4; ++j) {
        BAR();
        const int n = n0 + j;
        const int buf = n & 1;
        if (n >= 3 && n < 515) {  // wave-uniform
          uint4 I0a, I0b, I1a, I1b, Ha, Hb;
          ld2(&hb[2][buf ^ 1][0][ks * 8], I0a, I0b);
          ld2(&hb[2][buf ^ 1][1][ks * 8], I1a, I1b);
          ld2(&hb[3][buf ^ 1][1][ks * 8], Ha, Hb);
          float acc0 = dot16v(wih, I0a, I0b) + dot16v(whh, Ha, Hb);
          acc0 = dpp_add<0xB1>(acc0) + bias;
          const float hv0 = tanh_fast(acc0);
          store_h(3, buf, 0, hv0);
          if (ks == 0) h3f[buf][0][h] = hv0;  // exact f32 handoff to wave0
          uint4 Ga, Gb;
          ld2(&hb[3][buf][0][ks * 8], Ga, Gb);
          float acc1 = dot16v(wih, I1a, I1b) + dot16v(whh, Ga, Gb);
          acc1 = dpp_add<0xB1>(acc1) + bias;
          const float hv1 = tanh_fast(acc1);
          store_h(3, buf, 1, hv1);
          if (ks == 0) h3f[buf][1][h] = hv1;
          if (n == 514 && ks == 0) hfin[(3 * BB + b) * HH + h] = hv1;
        }
      }
    }
  }
}

__global__ __launch_bounds__(256) void softmax_kernel(float* __restrict__ out) {
  __shared__ float red[8];
  const int row = blockIdx.x;
  float* p = out + (size_t)row * SS;
  const int tid = threadIdx.x;
  float4 v = ((const float4*)p)[tid];  // 256 threads x 4 = 1024 logits
  float m = fmaxf(fmaxf(v.x, v.y), fmaxf(v.z, v.w));
#pragma unroll
  for (int d = 32; d >= 1; d >>= 1) m = fmaxf(m, __shfl_xor(m, d));
  if ((tid & 63) == 0) red[tid >> 6] = m;
  __syncthreads();
  m = fmaxf(fmaxf(red[0], red[1]), fmaxf(red[2], red[3]));
  const float e0 = __expf(v.x - m), e1 = __expf(v.y - m);
  const float e2 = __expf(v.z - m), e3 = __expf(v.w - m);
  float s = (e0 + e1) + (e2 + e3);
#pragma unroll
  for (int d = 32; d >= 1; d >>= 1) s += __shfl_xor(s, d);
  if ((tid & 63) == 0) red[4 + (tid >> 6)] = s;
  __syncthreads();
  s = (red[4] + red[5]) + (red[6] + red[7]);
  const float inv = 1.0f / s;
  float4 o;
  o.x = e0 * inv; o.y = e1 * inv; o.z = e2 * inv; o.w = e3 * inv;
  ((float4*)p)[tid] = o;
}

extern "C" void kernel_launch(void* const* d_in, const int* in_sizes, int n_in,
                              void* d_out, int out_size, void* d_ws, size_t ws_size,
                              hipStream_t stream) {
  const float* x         = (const float*)d_in[0];
  const float* h_state   = (const float*)d_in[1];
  const float* W_ih0     = (const float*)d_in[2];
  const float* W_ih_rest = (const float*)d_in[3];
  const float* W_hh      = (const float*)d_in[4];
  const float* b_ih      = (const float*)d_in[5];
  const float* b_hh      = (const float*)d_in[6];
  const float* fc_w      = (const float*)d_in[7];
  const float* fc_b      = (const float*)d_in[8];
  float* out = (float*)d_out;
  float* u0  = (float*)d_ws;  // [B,S,32] fp32 = 67 MB scratch

  hipLaunchKernelGGL(u0_kernel, dim3((BB * SS) / 256), dim3(256), 0, stream,
                     x, W_ih0, b_ih, b_hh, u0);
  hipLaunchKernelGGL(rnn_kernel, dim3(BB), dim3(256), 0, stream,
                     u0, h_state, W_ih_rest, W_hh, b_ih, b_hh, fc_w, fc_b, out);
  hipLaunchKernelGGL(softmax_kernel, dim3(BB), dim3(256), 0, stream, out);
}